// Round 1
// baseline (1119.985 us; speedup 1.0000x reference)
//
#include <hip/hip_runtime.h>
#include <hip/hip_bf16.h>
#include <stdint.h>

#define NR 8192
#define FD 512

typedef __attribute__((ext_vector_type(8))) short s8v;   // 8 bf16 (4 VGPRs) - MFMA A/B frag
typedef __attribute__((ext_vector_type(4))) float f32x4; // MFMA C/D frag

static __device__ __forceinline__ short bf16_rtne(float x) {
    union { float f; uint32_t u; } v; v.f = x;
    uint32_t r = (v.u + 0x7FFFu + ((v.u >> 16) & 1u)) >> 16;
    return (short)r;
}
static __device__ __forceinline__ float bf16_to_f32(short s) {
    union { uint32_t u; float f; } v; v.u = ((uint32_t)(uint16_t)s) << 16;
    return v.f;
}

// ---------------- K0a: fp32 -> bf16 convert (inp) ----------------
__global__ void k_convert(const float* __restrict__ in, short* __restrict__ out) {
    int i = blockIdx.x * blockDim.x + threadIdx.x;   // one float4 per thread
    float4 v = ((const float4*)in)[i];
    s8v dummy; (void)dummy;
    short4 s;
    s.x = bf16_rtne(v.x); s.y = bf16_rtne(v.y);
    s.z = bf16_rtne(v.z); s.w = bf16_rtne(v.w);
    ((short4*)out)[i] = s;
}

// ---------------- K0b: W1 [k][n] -> W1T bf16 [n][k] ----------------
__global__ void k_w1t(const float* __restrict__ W1, short* __restrict__ W1T) {
    int i = blockIdx.x * 256 + threadIdx.x;  // 512*512
    int k = i & 511, n = i >> 9;
    W1T[(size_t)n * 512 + k] = bf16_rtne(W1[(size_t)k * 512 + n]);
}

// ---------------- K1: h = inp @ W1 + b1  (bf16 MFMA, direct global frags) ----
// block: 64 rows x 256 cols, 512 threads (8 waves as 2x4)
__launch_bounds__(512)
__global__ void k_gemm_h(const short* __restrict__ A,   // inp bf16 [8192][512]
                         const short* __restrict__ BT,  // W1T bf16 [512][512]
                         const float* __restrict__ b1,
                         short* __restrict__ H)         // bf16 [8192][512]
{
    const int lane = threadIdx.x & 63;
    const int w    = threadIdx.x >> 6;
    const int wm   = w >> 2;          // 0..1
    const int wn   = w & 3;           // 0..3
    const int m    = lane & 15;
    const int q    = lane >> 4;
    const int r0   = blockIdx.x * 64 + wm * 32;
    const int c0   = blockIdx.y * 256 + wn * 64;

    f32x4 acc[2][4] = {};
#pragma unroll 1
    for (int k0 = 0; k0 < 512; k0 += 32) {
        s8v a[2], b[4];
#pragma unroll
        for (int rt = 0; rt < 2; ++rt)
            a[rt] = *(const s8v*)(A + (size_t)(r0 + rt * 16 + m) * 512 + k0 + q * 8);
#pragma unroll
        for (int nt = 0; nt < 4; ++nt)
            b[nt] = *(const s8v*)(BT + (size_t)(c0 + nt * 16 + m) * 512 + k0 + q * 8);
#pragma unroll
        for (int rt = 0; rt < 2; ++rt)
#pragma unroll
            for (int nt = 0; nt < 4; ++nt)
                acc[rt][nt] = __builtin_amdgcn_mfma_f32_16x16x32_bf16(a[rt], b[nt], acc[rt][nt], 0, 0, 0);
    }
#pragma unroll
    for (int rt = 0; rt < 2; ++rt)
#pragma unroll
        for (int nt = 0; nt < 4; ++nt)
#pragma unroll
            for (int r = 0; r < 4; ++r) {
                int row = r0 + rt * 16 + q * 4 + r;   // C layout: col=lane&15, row=quad*4+reg
                int col = c0 + nt * 16 + m;
                H[(size_t)row * 512 + col] = bf16_rtne(acc[rt][nt][r] + b1[col]);
            }
}

// ---------------- K2: transpose H -> HT [512][8192] ----------------
__global__ void k_transpose(const short* __restrict__ H, short* __restrict__ HT) {
    __shared__ short tile[64][66];
    const int t  = threadIdx.x;        // 256
    const int r0 = blockIdx.x * 64;    // 128 row-blocks
    const int c0 = blockIdx.y * 64;    // 8 col-blocks
#pragma unroll
    for (int pass = 0; pass < 2; ++pass) {
        int rr = (t >> 3) + pass * 32;
        int cc = (t & 7) * 8;
        s8v v = *(const s8v*)(H + (size_t)(r0 + rr) * 512 + c0 + cc);
#pragma unroll
        for (int i = 0; i < 8; ++i) tile[rr][cc + i] = v[i];
    }
    __syncthreads();
#pragma unroll
    for (int pass = 0; pass < 2; ++pass) {
        int c  = (t >> 3) + pass * 32;
        int rp = (t & 7) * 8;
        s8v v;
#pragma unroll
        for (int i = 0; i < 8; ++i) v[i] = tile[rp + i][c];
        *(s8v*)(HT + (size_t)(c0 + c) * 8192 + r0 + rp) = v;
    }
}

// ---------------- K3: f1 = h@a1, f2s = h@a2 + b2 (one wave per row) --------
__global__ void k_f1f2(const short* __restrict__ H, const float* __restrict__ a1,
                       const float* __restrict__ a2, const float* __restrict__ b2,
                       float* __restrict__ f1, float* __restrict__ f2s)
{
    const int lane = threadIdx.x & 63;
    const int row  = blockIdx.x * 4 + (threadIdx.x >> 6);
    s8v hv = *(const s8v*)(H + (size_t)row * 512 + lane * 8);
    float4 a1l = ((const float4*)(a1 + lane * 8))[0];
    float4 a1h = ((const float4*)(a1 + lane * 8))[1];
    float4 a2l = ((const float4*)(a2 + lane * 8))[0];
    float4 a2h = ((const float4*)(a2 + lane * 8))[1];
    float hf[8];
#pragma unroll
    for (int i = 0; i < 8; ++i) hf[i] = bf16_to_f32(hv[i]);
    float s1 = hf[0] * a1l.x + hf[1] * a1l.y + hf[2] * a1l.z + hf[3] * a1l.w
             + hf[4] * a1h.x + hf[5] * a1h.y + hf[6] * a1h.z + hf[7] * a1h.w;
    float s2 = hf[0] * a2l.x + hf[1] * a2l.y + hf[2] * a2l.z + hf[3] * a2l.w
             + hf[4] * a2h.x + hf[5] * a2h.y + hf[6] * a2h.z + hf[7] * a2h.w;
#pragma unroll
    for (int o = 32; o > 0; o >>= 1) {
        s1 += __shfl_xor(s1, o);
        s2 += __shfl_xor(s2, o);
    }
    if (lane == 0) {
        f1[row]  = s1;
        f2s[row] = s2 + b2[0];
    }
}

// ---------------- K4: fused masked-softmax attention @ h ----------------
// block: 32 rows x all 512 cols, 512 threads (8 waves: wm in {0,1} -> 16-row
// tile, wn in {0..3} -> 128-col group). A-operand (softmax weights) generated
// in-register from adj/f1/f2; B-operand loaded direct from HT (k-contiguous).
__launch_bounds__(512)
__global__ void k_attn(const int* __restrict__ adj,
                       const short* __restrict__ HT,   // bf16 [512][8192]
                       const float* __restrict__ f1,
                       const float* __restrict__ f2s,
                       float* __restrict__ out)        // fp32 [8192][512]
{
    const int lane = threadIdx.x & 63;
    const int w    = threadIdx.x >> 6;
    const int wm   = w >> 2;
    const int wn   = w & 3;
    const int m    = lane & 15;
    const int q    = lane >> 4;
    const int r0   = blockIdx.x * 32;
    const int row  = r0 + wm * 16 + m;     // this lane's A-row
    const float f1v = f1[row];

    f32x4 acc[8] = {};
    float denom = 0.f;

    const int*   adjp = adj + (size_t)row * 8192 + q * 8;
    const float* f2p  = f2s + q * 8;

#pragma unroll 1
    for (int j0 = 0; j0 < 8192; j0 += 32) {
        int4   aj0 = *(const int4*)(adjp + j0);
        int4   aj1 = *(const int4*)(adjp + j0 + 4);
        float4 f20 = *(const float4*)(f2p + j0);
        float4 f21 = *(const float4*)(f2p + j0 + 4);
        s8v b[8];
#pragma unroll
        for (int nt = 0; nt < 8; ++nt) {
            int col = wn * 128 + nt * 16 + m;
            b[nt] = *(const s8v*)(HT + (size_t)col * 8192 + j0 + q * 8);
        }
        s8v afr;
#define GAT_W(AJ, F2, IDX)                                   \
        { float s_ = f1v + (F2);                              \
          float e_ = fmaxf(s_, 0.2f * s_);                    \
          float we_ = __expf(e_);                             \
          float wj_ = ((AJ) != 0) ? we_ : 0.0f;               \
          denom += wj_;                                       \
          afr[IDX] = bf16_rtne(wj_); }
        GAT_W(aj0.x, f20.x, 0) GAT_W(aj0.y, f20.y, 1)
        GAT_W(aj0.z, f20.z, 2) GAT_W(aj0.w, f20.w, 3)
        GAT_W(aj1.x, f21.x, 4) GAT_W(aj1.y, f21.y, 5)
        GAT_W(aj1.z, f21.z, 6) GAT_W(aj1.w, f21.w, 7)
#undef GAT_W
#pragma unroll
        for (int nt = 0; nt < 8; ++nt)
            acc[nt] = __builtin_amdgcn_mfma_f32_16x16x32_bf16(afr, b[nt], acc[nt], 0, 0, 0);
    }

    // denom: sum the 4 quads (each quad covered a disjoint k-slice)
    denom += __shfl_xor(denom, 16);
    denom += __shfl_xor(denom, 32);
    // all lanes now hold D(row = wm*16 + (lane&15)); fetch D for C-frag rows
    float dr[4];
#pragma unroll
    for (int r = 0; r < 4; ++r) dr[r] = __shfl(denom, q * 4 + r);

#pragma unroll
    for (int nt = 0; nt < 8; ++nt) {
        int col = wn * 128 + nt * 16 + m;
#pragma unroll
        for (int r = 0; r < 4; ++r) {
            int orow = r0 + wm * 16 + q * 4 + r;
            float v = acc[nt][r] / dr[r];
            float o = (v > 0.f) ? v : (__expf(v) - 1.0f);
            out[(size_t)orow * 512 + col] = o;
        }
    }
}

extern "C" void kernel_launch(void* const* d_in, const int* in_sizes, int n_in,
                              void* d_out, int out_size, void* d_ws, size_t ws_size,
                              hipStream_t stream) {
    const float* inp = (const float*)d_in[0];
    const int*   adj = (const int*)d_in[1];
    const float* W1  = (const float*)d_in[2];
    const float* b1  = (const float*)d_in[3];
    const float* a1  = (const float*)d_in[4];
    const float* a2  = (const float*)d_in[5];
    const float* b2  = (const float*)d_in[6];
    float* out = (float*)d_out;

    // workspace layout (bf16 = short)
    short* inp_bf = (short*)d_ws;                       // 8192*512
    short* w1t    = inp_bf + (size_t)NR * FD;           // 512*512
    short* h      = w1t + (size_t)FD * FD;              // 8192*512
    short* ht     = h + (size_t)NR * FD;                // 512*8192
    float* f1     = (float*)(ht + (size_t)FD * NR);     // 8192
    float* f2s    = f1 + NR;                            // 8192

    k_convert<<<(NR * FD / 4) / 256, 256, 0, stream>>>(inp, inp_bf);
    k_w1t<<<(FD * FD) / 256, 256, 0, stream>>>(W1, w1t);
    dim3 g1(NR / 64, FD / 256);
    k_gemm_h<<<g1, 512, 0, stream>>>(inp_bf, w1t, b1, h);
    dim3 g2(NR / 64, FD / 64);
    k_transpose<<<g2, 256, 0, stream>>>(h, ht);
    k_f1f2<<<NR / 4, 256, 0, stream>>>(h, a1, a2, b2, f1, f2s);
    k_attn<<<NR / 32, 512, 0, stream>>>(adj, ht, f1, f2s, out);
}

// Round 2
// 962.445 us; speedup vs baseline: 1.1637x; 1.1637x over previous
//
#include <hip/hip_runtime.h>
#include <hip/hip_bf16.h>
#include <stdint.h>

#define NR 8192
#define FD 512

typedef __attribute__((ext_vector_type(8))) short s8v;   // 8 bf16 (4 VGPRs) - MFMA A/B frag
typedef __attribute__((ext_vector_type(4))) float f32x4; // MFMA C/D frag

static __device__ __forceinline__ short bf16_rtne(float x) {
    union { float f; uint32_t u; } v; v.f = x;
    uint32_t r = (v.u + 0x7FFFu + ((v.u >> 16) & 1u)) >> 16;
    return (short)r;
}
static __device__ __forceinline__ float bf16_to_f32(short s) {
    union { uint32_t u; float f; } v; v.u = ((uint32_t)(uint16_t)s) << 16;
    return v.f;
}

// ---------------- K0a: fp32 -> bf16 convert (inp) ----------------
__global__ void k_convert(const float* __restrict__ in, short* __restrict__ out) {
    int i = blockIdx.x * blockDim.x + threadIdx.x;   // one float4 per thread
    float4 v = ((const float4*)in)[i];
    short4 s;
    s.x = bf16_rtne(v.x); s.y = bf16_rtne(v.y);
    s.z = bf16_rtne(v.z); s.w = bf16_rtne(v.w);
    ((short4*)out)[i] = s;
}

// ---------------- K0b: W1 [k][n] -> W1T bf16 [n][k] ----------------
__global__ void k_w1t(const float* __restrict__ W1, short* __restrict__ W1T) {
    int i = blockIdx.x * 256 + threadIdx.x;  // 512*512
    int k = i & 511, n = i >> 9;
    W1T[(size_t)n * 512 + k] = bf16_rtne(W1[(size_t)k * 512 + n]);
}

// ---------------- K1: h = inp @ W1 + b1  (bf16 MFMA, direct global frags) ----
__launch_bounds__(512)
__global__ void k_gemm_h(const short* __restrict__ A,   // inp bf16 [8192][512]
                         const short* __restrict__ BT,  // W1T bf16 [512][512]
                         const float* __restrict__ b1,
                         short* __restrict__ H)         // bf16 [8192][512]
{
    const int lane = threadIdx.x & 63;
    const int w    = threadIdx.x >> 6;
    const int wm   = w >> 2;          // 0..1
    const int wn   = w & 3;           // 0..3
    const int m    = lane & 15;
    const int q    = lane >> 4;
    const int r0   = blockIdx.x * 64 + wm * 32;
    const int c0   = blockIdx.y * 256 + wn * 64;

    f32x4 acc[2][4] = {};
#pragma unroll 1
    for (int k0 = 0; k0 < 512; k0 += 32) {
        s8v a[2], b[4];
#pragma unroll
        for (int rt = 0; rt < 2; ++rt)
            a[rt] = *(const s8v*)(A + (size_t)(r0 + rt * 16 + m) * 512 + k0 + q * 8);
#pragma unroll
        for (int nt = 0; nt < 4; ++nt)
            b[nt] = *(const s8v*)(BT + (size_t)(c0 + nt * 16 + m) * 512 + k0 + q * 8);
#pragma unroll
        for (int rt = 0; rt < 2; ++rt)
#pragma unroll
            for (int nt = 0; nt < 4; ++nt)
                acc[rt][nt] = __builtin_amdgcn_mfma_f32_16x16x32_bf16(a[rt], b[nt], acc[rt][nt], 0, 0, 0);
    }
#pragma unroll
    for (int rt = 0; rt < 2; ++rt)
#pragma unroll
        for (int nt = 0; nt < 4; ++nt)
#pragma unroll
            for (int r = 0; r < 4; ++r) {
                int row = r0 + rt * 16 + q * 4 + r;
                int col = c0 + nt * 16 + m;
                H[(size_t)row * 512 + col] = bf16_rtne(acc[rt][nt][r] + b1[col]);
            }
}

// ---------------- K2: transpose H -> HT [512][8192] ----------------
__global__ void k_transpose(const short* __restrict__ H, short* __restrict__ HT) {
    __shared__ short tile[64][66];
    const int t  = threadIdx.x;        // 256
    const int r0 = blockIdx.x * 64;
    const int c0 = blockIdx.y * 64;
#pragma unroll
    for (int pass = 0; pass < 2; ++pass) {
        int rr = (t >> 3) + pass * 32;
        int cc = (t & 7) * 8;
        s8v v = *(const s8v*)(H + (size_t)(r0 + rr) * 512 + c0 + cc);
#pragma unroll
        for (int i = 0; i < 8; ++i) tile[rr][cc + i] = v[i];
    }
    __syncthreads();
#pragma unroll
    for (int pass = 0; pass < 2; ++pass) {
        int c  = (t >> 3) + pass * 32;
        int rp = (t & 7) * 8;
        s8v v;
#pragma unroll
        for (int i = 0; i < 8; ++i) v[i] = tile[rp + i][c];
        *(s8v*)(HT + (size_t)(c0 + c) * 8192 + r0 + rp) = v;
    }
}

// ---------------- K3: f1/f2 + separable-exp tables ----------------
// w_ij = adj ? exp(leaky(f1_i + f2s_j)) : 0
//      = adj ? (f2s_j >= -f1_i ? E1_i*E2_j : E1b_i*E2b_j) : 0
__global__ void k_f1f2(const short* __restrict__ H, const float* __restrict__ a1,
                       const float* __restrict__ a2, const float* __restrict__ b2,
                       float* __restrict__ f2s, float* __restrict__ nf1,
                       float* __restrict__ E1, float* __restrict__ E1b,
                       float* __restrict__ E2, float* __restrict__ E2b)
{
    const int lane = threadIdx.x & 63;
    const int row  = blockIdx.x * 4 + (threadIdx.x >> 6);
    s8v hv = *(const s8v*)(H + (size_t)row * 512 + lane * 8);
    float4 a1l = ((const float4*)(a1 + lane * 8))[0];
    float4 a1h = ((const float4*)(a1 + lane * 8))[1];
    float4 a2l = ((const float4*)(a2 + lane * 8))[0];
    float4 a2h = ((const float4*)(a2 + lane * 8))[1];
    float hf[8];
#pragma unroll
    for (int i = 0; i < 8; ++i) hf[i] = bf16_to_f32(hv[i]);
    float s1 = hf[0] * a1l.x + hf[1] * a1l.y + hf[2] * a1l.z + hf[3] * a1l.w
             + hf[4] * a1h.x + hf[5] * a1h.y + hf[6] * a1h.z + hf[7] * a1h.w;
    float s2 = hf[0] * a2l.x + hf[1] * a2l.y + hf[2] * a2l.z + hf[3] * a2l.w
             + hf[4] * a2h.x + hf[5] * a2h.y + hf[6] * a2h.z + hf[7] * a2h.w;
#pragma unroll
    for (int o = 32; o > 0; o >>= 1) {
        s1 += __shfl_xor(s1, o);
        s2 += __shfl_xor(s2, o);
    }
    if (lane == 0) {
        float f1v = s1;
        float f2v = s2 + b2[0];
        nf1[row]  = -f1v;
        E1[row]   = __expf(f1v);
        E1b[row]  = __expf(0.2f * f1v);
        f2s[row]  = f2v;
        E2[row]   = __expf(f2v);
        E2b[row]  = __expf(0.2f * f2v);
    }
}

// ---------------- K4: fused masked-softmax attention @ h ----------------
// Grid 512: bx&1 = col-half (256 cols), bx>>1 = 32-row band.
// 512 threads / 8 waves: wm = rows 16, wn = 64-col group. Weight tile (32x32)
// computed cooperatively (2 weights/thread) into padded LDS; waves ds_read
// A-frags. adj/E-tables/b-frags register-prefetched one iteration ahead.
#define BM 32
#define BK 32

__launch_bounds__(512, 4)
__global__ void k_attn(const int* __restrict__ adj,
                       const short* __restrict__ HT,   // bf16 [512][8192]
                       const float* __restrict__ f2s,
                       const float* __restrict__ nf1,
                       const float* __restrict__ E1,
                       const float* __restrict__ E1b,
                       const float* __restrict__ E2,
                       const float* __restrict__ E2b,
                       float* __restrict__ out)        // fp32 [8192][512]
{
    __shared__ __align__(16) short wtile[2][BM][48];   // stride 48: 16B-aligned rows, low conflicts
    __shared__ float denoms[BM];

    const int t    = threadIdx.x;
    const int lane = t & 63;
    const int w    = t >> 6;
    const int wm   = w >> 2;          // 0..1
    const int wn   = w & 3;           // 0..3
    const int m    = lane & 15;
    const int q    = lane >> 4;

    const int cb   = blockIdx.x & 1;
    const int r0   = (blockIdx.x >> 1) * BM;
    const int c0   = cb * 256 + wn * 64;

    // weight-producer coords: 16 threads per row, 2 j's per thread
    const int prow = t >> 4;          // 0..31
    const int pj   = (t & 15) * 2;    // 0..30

    const float nf1v = nf1[r0 + prow];
    const float e1v  = E1[r0 + prow];
    const float e1bv = E1b[r0 + prow];
    const int* adjp  = adj + (size_t)(r0 + prow) * NR + pj;

    f32x4 acc[4] = {};
    float dsum = 0.f;

    // prologue: loads for iteration 0
    int2   aj  = *(const int2*)(adjp);
    float2 fv  = *(const float2*)(f2s + pj);
    float2 e2  = *(const float2*)(E2 + pj);
    float2 e2b = *(const float2*)(E2b + pj);
    s8v b[4];
#pragma unroll
    for (int nt = 0; nt < 4; ++nt)
        b[nt] = *(const s8v*)(HT + (size_t)(c0 + nt * 16 + m) * NR + q * 8);

    int p = 0;
#pragma unroll 1
    for (int it = 0; it < NR / BK; ++it) {
        const int j0n = ((it + 1) * BK) & (NR - 1);   // wraps on last iter (dummy)
        // prefetch next iteration
        int2   ajn  = *(const int2*)(adjp + j0n);
        float2 fvn  = *(const float2*)(f2s + j0n + pj);
        float2 e2n  = *(const float2*)(E2 + j0n + pj);
        float2 e2bn = *(const float2*)(E2b + j0n + pj);
        s8v bn[4];
#pragma unroll
        for (int nt = 0; nt < 4; ++nt)
            bn[nt] = *(const s8v*)(HT + (size_t)(c0 + nt * 16 + m) * NR + j0n + q * 8);

        // current weights -> LDS tile
        float ta0 = e1v * e2.x,  tb0 = e1bv * e2b.x;
        float wv0 = (fv.x >= nf1v) ? ta0 : tb0;
        float w0  = (aj.x != 0) ? wv0 : 0.f;
        float ta1 = e1v * e2.y,  tb1 = e1bv * e2b.y;
        float wv1 = (fv.y >= nf1v) ? ta1 : tb1;
        float w1  = (aj.y != 0) ? wv1 : 0.f;
        dsum += w0 + w1;
        short2 wp; wp.x = bf16_rtne(w0); wp.y = bf16_rtne(w1);
        *(short2*)&wtile[p][prow][pj] = wp;

        __syncthreads();

        s8v afr = *(const s8v*)&wtile[p][wm * 16 + m][q * 8];
#pragma unroll
        for (int nt = 0; nt < 4; ++nt)
            acc[nt] = __builtin_amdgcn_mfma_f32_16x16x32_bf16(afr, b[nt], acc[nt], 0, 0, 0);

        aj = ajn; fv = fvn; e2 = e2n; e2b = e2bn;
#pragma unroll
        for (int nt = 0; nt < 4; ++nt) b[nt] = bn[nt];
        p ^= 1;
    }

    // per-row denominator: reduce dsum over the 16 producer threads of each row
#pragma unroll
    for (int o = 1; o < 16; o <<= 1) dsum += __shfl_xor(dsum, o);
    if ((lane & 15) == 0) denoms[prow] = dsum;
    __syncthreads();

    float dr[4];
#pragma unroll
    for (int r = 0; r < 4; ++r) dr[r] = denoms[wm * 16 + q * 4 + r];

#pragma unroll
    for (int nt = 0; nt < 4; ++nt) {
        int col = c0 + nt * 16 + m;
#pragma unroll
        for (int r = 0; r < 4; ++r) {
            int orow = r0 + wm * 16 + q * 4 + r;
            float v = acc[nt][r] / dr[r];
            out[(size_t)orow * FD + col] = (v > 0.f) ? v : (__expf(v) - 1.0f);
        }
    }
}

extern "C" void kernel_launch(void* const* d_in, const int* in_sizes, int n_in,
                              void* d_out, int out_size, void* d_ws, size_t ws_size,
                              hipStream_t stream) {
    const float* inp = (const float*)d_in[0];
    const int*   adj = (const int*)d_in[1];
    const float* W1  = (const float*)d_in[2];
    const float* b1  = (const float*)d_in[3];
    const float* a1  = (const float*)d_in[4];
    const float* a2  = (const float*)d_in[5];
    const float* b2  = (const float*)d_in[6];
    float* out = (float*)d_out;

    // workspace layout (bf16 = short)
    short* inp_bf = (short*)d_ws;                       // 8192*512
    short* w1t    = inp_bf + (size_t)NR * FD;           // 512*512
    short* h      = w1t + (size_t)FD * FD;              // 8192*512
    short* ht     = h + (size_t)NR * FD;                // 512*8192
    float* f2s    = (float*)(ht + (size_t)FD * NR);     // 8192 each below
    float* nf1    = f2s + NR;
    float* E1     = nf1 + NR;
    float* E1b    = E1 + NR;
    float* E2     = E1b + NR;
    float* E2b    = E2 + NR;

    k_convert<<<(NR * FD / 4) / 256, 256, 0, stream>>>(inp, inp_bf);
    k_w1t<<<(FD * FD) / 256, 256, 0, stream>>>(W1, w1t);
    dim3 g1(NR / 64, FD / 256);
    k_gemm_h<<<g1, 512, 0, stream>>>(inp_bf, w1t, b1, h);
    dim3 g2(NR / 64, FD / 64);
    k_transpose<<<g2, 256, 0, stream>>>(h, ht);
    k_f1f2<<<NR / 4, 256, 0, stream>>>(h, a1, a2, b2, f2s, nf1, E1, E1b, E2, E2b);
    k_attn<<<(NR / BM) * 2, 512, 0, stream>>>(adj, ht, f2s, nf1, E1, E1b, E2, E2b, out);
}

// Round 3
// 655.528 us; speedup vs baseline: 1.7085x; 1.4682x over previous
//
#include <hip/hip_runtime.h>
#include <hip/hip_bf16.h>
#include <stdint.h>

#define NR 8192
#define FD 512

typedef __attribute__((ext_vector_type(8))) short s8v;   // 8 bf16 (4 VGPRs) - MFMA A/B frag
typedef __attribute__((ext_vector_type(4))) float f32x4; // MFMA C/D frag

static __device__ __forceinline__ short bf16_rtne(float x) {
    union { float f; uint32_t u; } v; v.f = x;
    uint32_t r = (v.u + 0x7FFFu + ((v.u >> 16) & 1u)) >> 16;
    return (short)r;
}
static __device__ __forceinline__ float bf16_to_f32(short s) {
    union { uint32_t u; float f; } v; v.u = ((uint32_t)(uint16_t)s) << 16;
    return v.f;
}
static __device__ __forceinline__ float asfloat_u32(uint32_t u) {
    union { uint32_t u; float f; } v; v.u = u; return v.f;
}

// ---------------- K0a: fp32 -> bf16 convert (inp) ----------------
__global__ void k_convert(const float* __restrict__ in, short* __restrict__ out) {
    int i = blockIdx.x * blockDim.x + threadIdx.x;   // one float4 per thread
    float4 v = ((const float4*)in)[i];
    short4 s;
    s.x = bf16_rtne(v.x); s.y = bf16_rtne(v.y);
    s.z = bf16_rtne(v.z); s.w = bf16_rtne(v.w);
    ((short4*)out)[i] = s;
}

// ---------------- K0b: W1 [k][n] -> W1T bf16 [n][k] ----------------
__global__ void k_w1t(const float* __restrict__ W1, short* __restrict__ W1T) {
    int i = blockIdx.x * 256 + threadIdx.x;  // 512*512
    int k = i & 511, n = i >> 9;
    W1T[(size_t)n * 512 + k] = bf16_rtne(W1[(size_t)k * 512 + n]);
}

// ---------------- K1: h = inp @ W1 + b1  (bf16 MFMA, direct global frags) ----
__launch_bounds__(512)
__global__ void k_gemm_h(const short* __restrict__ A,   // inp bf16 [8192][512]
                         const short* __restrict__ BT,  // W1T bf16 [512][512]
                         const float* __restrict__ b1,
                         short* __restrict__ H)         // bf16 [8192][512]
{
    const int lane = threadIdx.x & 63;
    const int w    = threadIdx.x >> 6;
    const int wm   = w >> 2;          // 0..1
    const int wn   = w & 3;           // 0..3
    const int m    = lane & 15;
    const int q    = lane >> 4;
    const int r0   = blockIdx.x * 64 + wm * 32;
    const int c0   = blockIdx.y * 256 + wn * 64;

    f32x4 acc[2][4] = {};
#pragma unroll 1
    for (int k0 = 0; k0 < 512; k0 += 32) {
        s8v a[2], b[4];
#pragma unroll
        for (int rt = 0; rt < 2; ++rt)
            a[rt] = *(const s8v*)(A + (size_t)(r0 + rt * 16 + m) * 512 + k0 + q * 8);
#pragma unroll
        for (int nt = 0; nt < 4; ++nt)
            b[nt] = *(const s8v*)(BT + (size_t)(c0 + nt * 16 + m) * 512 + k0 + q * 8);
#pragma unroll
        for (int rt = 0; rt < 2; ++rt)
#pragma unroll
            for (int nt = 0; nt < 4; ++nt)
                acc[rt][nt] = __builtin_amdgcn_mfma_f32_16x16x32_bf16(a[rt], b[nt], acc[rt][nt], 0, 0, 0);
    }
#pragma unroll
    for (int rt = 0; rt < 2; ++rt)
#pragma unroll
        for (int nt = 0; nt < 4; ++nt)
#pragma unroll
            for (int r = 0; r < 4; ++r) {
                int row = r0 + rt * 16 + q * 4 + r;
                int col = c0 + nt * 16 + m;
                H[(size_t)row * 512 + col] = bf16_rtne(acc[rt][nt][r] + b1[col]);
            }
}

// ---------------- K2: transpose H -> HT [512][8192] ----------------
__global__ void k_transpose(const short* __restrict__ H, short* __restrict__ HT) {
    __shared__ short tile[64][66];
    const int t  = threadIdx.x;        // 256
    const int r0 = blockIdx.x * 64;
    const int c0 = blockIdx.y * 64;
#pragma unroll
    for (int pass = 0; pass < 2; ++pass) {
        int rr = (t >> 3) + pass * 32;
        int cc = (t & 7) * 8;
        s8v v = *(const s8v*)(H + (size_t)(r0 + rr) * 512 + c0 + cc);
#pragma unroll
        for (int i = 0; i < 8; ++i) tile[rr][cc + i] = v[i];
    }
    __syncthreads();
#pragma unroll
    for (int pass = 0; pass < 2; ++pass) {
        int c  = (t >> 3) + pass * 32;
        int rp = (t & 7) * 8;
        s8v v;
#pragma unroll
        for (int i = 0; i < 8; ++i) v[i] = tile[rp + i][c];
        *(s8v*)(HT + (size_t)(c0 + c) * 8192 + r0 + rp) = v;
    }
}

// ---------------- K3: f1/f2 + separable-exp tables ----------------
// w_ij = adj ? exp(leaky(f1_i + f2s_j)) : 0
//      = adj ? (f2s_j >= -f1_i ? E1_i*E2_j : E1b_i*E2b_j) : 0
// per-row: nf1, E1, E1b (fp32); per-col: jtab = {bf16(E2)|bf16(E2b)<<16, f2s}
__global__ void k_f1f2(const short* __restrict__ H, const float* __restrict__ a1,
                       const float* __restrict__ a2, const float* __restrict__ b2,
                       float* __restrict__ nf1, float* __restrict__ E1,
                       float* __restrict__ E1b, uint2* __restrict__ jtab)
{
    const int lane = threadIdx.x & 63;
    const int row  = blockIdx.x * 4 + (threadIdx.x >> 6);
    s8v hv = *(const s8v*)(H + (size_t)row * 512 + lane * 8);
    float4 a1l = ((const float4*)(a1 + lane * 8))[0];
    float4 a1h = ((const float4*)(a1 + lane * 8))[1];
    float4 a2l = ((const float4*)(a2 + lane * 8))[0];
    float4 a2h = ((const float4*)(a2 + lane * 8))[1];
    float hf[8];
#pragma unroll
    for (int i = 0; i < 8; ++i) hf[i] = bf16_to_f32(hv[i]);
    float s1 = hf[0] * a1l.x + hf[1] * a1l.y + hf[2] * a1l.z + hf[3] * a1l.w
             + hf[4] * a1h.x + hf[5] * a1h.y + hf[6] * a1h.z + hf[7] * a1h.w;
    float s2 = hf[0] * a2l.x + hf[1] * a2l.y + hf[2] * a2l.z + hf[3] * a2l.w
             + hf[4] * a2h.x + hf[5] * a2h.y + hf[6] * a2h.z + hf[7] * a2h.w;
#pragma unroll
    for (int o = 32; o > 0; o >>= 1) {
        s1 += __shfl_xor(s1, o);
        s2 += __shfl_xor(s2, o);
    }
    if (lane == 0) {
        float f1v = s1;
        float f2v = s2 + b2[0];
        nf1[row]  = -f1v;
        E1[row]   = __expf(f1v);
        E1b[row]  = __expf(0.2f * f1v);
        uint32_t p = (uint32_t)(uint16_t)bf16_rtne(__expf(f2v))
                   | ((uint32_t)(uint16_t)bf16_rtne(__expf(0.2f * f2v)) << 16);
        union { float f; uint32_t u; } fb; fb.f = f2v;
        jtab[row] = make_uint2(p, fb.u);
    }
}

// ---------------- K4: fused masked-softmax attention @ h ----------------
// Grid 256 (one 32-row band per block). 512 threads / 8 waves; wave w owns
// cols w*64..w*64+63, all 32 rows (af[2] per k-step). Per 256-j chunk:
//   phase1: each thread builds 16 weights of one row into XOR-swizzled LDS
//   barrier (32 total, not 256)
//   phase2: 8 barrier-free k-steps: ds_read A-frags + global B-frags + MFMA
#define BM 32
#define BKC 256

__launch_bounds__(512, 2)
__global__ void k_attn(const int* __restrict__ adj,
                       const short* __restrict__ HT,   // bf16 [512][8192]
                       const float* __restrict__ nf1,
                       const float* __restrict__ E1,
                       const float* __restrict__ E1b,
                       const uint2* __restrict__ jtab,
                       float* __restrict__ out)        // fp32 [8192][512]
{
    __shared__ __align__(16) short wt[2][BM * BKC];    // 32 KB, XOR-swizzled
    __shared__ float denoms[BM];

    const int t    = threadIdx.x;
    const int lane = t & 63;
    const int w    = t >> 6;           // wave 0..7 -> 64-col group
    const int m    = lane & 15;
    const int q    = lane >> 4;
    const int r0   = blockIdx.x * BM;
    const int c0   = w * 64;

    // weight-producer coords: 16 threads per row, 16 j's per thread
    const int prow = t >> 4;           // 0..31
    const int jc   = t & 15;           // j-chunk within 256

    const float nf1v = nf1[r0 + prow];
    const float E1v  = E1[r0 + prow];
    const float E1bv = E1b[r0 + prow];
    const int*  adjp = adj + (size_t)(r0 + prow) * NR + jc * 16;
    const uint4* tabp = (const uint4*)jtab + jc * 8;   // 2 j per uint4

    f32x4 acc[2][4] = {};
    float dsum = 0.f;

#pragma unroll 1
    for (int ch = 0; ch < NR / BKC; ++ch) {
        const int p = ch & 1;
        // ---- phase 1: build 16 weights for row (r0+prow), j = ch*256 + jc*16 .. +15
        int4 aj4[4];
        uint4 tb[8];
#pragma unroll
        for (int g = 0; g < 4; ++g) aj4[g] = ((const int4*)(adjp + ch * BKC))[g];
#pragma unroll
        for (int g = 0; g < 8; ++g) tb[g] = tabp[ch * 128 + g];

        s8v wv[2];
        float dadd = 0.f;
#pragma unroll
        for (int jj = 0; jj < 16; ++jj) {
            int a = ((const int*)aj4)[jj];
            uint32_t w0 = (jj & 1) ? tb[jj >> 1].z : tb[jj >> 1].x;
            uint32_t w1 = (jj & 1) ? tb[jj >> 1].w : tb[jj >> 1].y;
            float e2  = asfloat_u32(w0 << 16);
            float e2b = asfloat_u32(w0 & 0xFFFF0000u);
            float f2  = asfloat_u32(w1);
            bool cnd  = (f2 >= nf1v);
            float wgt = (cnd ? E1v : E1bv) * (cnd ? e2 : e2b);
            wgt = (a != 0) ? wgt : 0.f;
            dadd += wgt;
            wv[jj >> 3][jj & 7] = bf16_rtne(wgt);
        }
        dsum += dadd;
#pragma unroll
        for (int s = 0; s < 2; ++s) {
            int jb = jc * 2 + s;
            int off = prow * BKC + ((jb ^ prow) << 3);
            *(s8v*)&wt[p][off] = wv[s];
        }

        __syncthreads();

        // ---- phase 2: 8 barrier-free k-steps
#pragma unroll
        for (int kk = 0; kk < 8; ++kk) {
            const int j0 = ch * BKC + kk * 32;
            s8v b[4];
#pragma unroll
            for (int nt = 0; nt < 4; ++nt)
                b[nt] = *(const s8v*)(HT + (size_t)(c0 + nt * 16 + m) * NR + j0 + q * 8);
            const int jb = kk * 4 + q;
            s8v af0 = *(const s8v*)&wt[p][m * BKC + ((jb ^ m) << 3)];
            s8v af1 = *(const s8v*)&wt[p][(m + 16) * BKC + (((jb ^ (m + 16)) & 31) << 3)];
#pragma unroll
            for (int nt = 0; nt < 4; ++nt) {
                acc[0][nt] = __builtin_amdgcn_mfma_f32_16x16x32_bf16(af0, b[nt], acc[0][nt], 0, 0, 0);
                acc[1][nt] = __builtin_amdgcn_mfma_f32_16x16x32_bf16(af1, b[nt], acc[1][nt], 0, 0, 0);
            }
        }
    }

    // ---- denominators: reduce over the 16 producer threads of each row
#pragma unroll
    for (int o = 1; o < 16; o <<= 1) dsum += __shfl_xor(dsum, o);
    if (jc == 0) denoms[prow] = dsum;
    __syncthreads();

#pragma unroll
    for (int rt = 0; rt < 2; ++rt)
#pragma unroll
        for (int r = 0; r < 4; ++r) {
            float dr = denoms[rt * 16 + q * 4 + r];
            int orow = r0 + rt * 16 + q * 4 + r;
#pragma unroll
            for (int nt = 0; nt < 4; ++nt) {
                int col = c0 + nt * 16 + m;
                float v = acc[rt][nt][r] / dr;
                out[(size_t)orow * FD + col] = (v > 0.f) ? v : (__expf(v) - 1.0f);
            }
        }
}

extern "C" void kernel_launch(void* const* d_in, const int* in_sizes, int n_in,
                              void* d_out, int out_size, void* d_ws, size_t ws_size,
                              hipStream_t stream) {
    const float* inp = (const float*)d_in[0];
    const int*   adj = (const int*)d_in[1];
    const float* W1  = (const float*)d_in[2];
    const float* b1  = (const float*)d_in[3];
    const float* a1  = (const float*)d_in[4];
    const float* a2  = (const float*)d_in[5];
    const float* b2  = (const float*)d_in[6];
    float* out = (float*)d_out;

    // workspace layout (bf16 = short)
    short* inp_bf = (short*)d_ws;                       // 8192*512
    short* w1t    = inp_bf + (size_t)NR * FD;           // 512*512
    short* h      = w1t + (size_t)FD * FD;              // 8192*512
    short* ht     = h + (size_t)NR * FD;                // 512*8192
    float* nf1    = (float*)(ht + (size_t)FD * NR);     // 8192
    float* E1     = nf1 + NR;                           // 8192
    float* E1b    = E1 + NR;                            // 8192
    uint2* jtab   = (uint2*)(E1b + NR);                 // 8192 * 8B

    k_convert<<<(NR * FD / 4) / 256, 256, 0, stream>>>(inp, inp_bf);
    k_w1t<<<(FD * FD) / 256, 256, 0, stream>>>(W1, w1t);
    dim3 g1(NR / 64, FD / 256);
    k_gemm_h<<<g1, 512, 0, stream>>>(inp_bf, w1t, b1, h);
    dim3 g2(NR / 64, FD / 64);
    k_transpose<<<g2, 256, 0, stream>>>(h, ht);
    k_f1f2<<<NR / 4, 256, 0, stream>>>(h, a1, a2, b2, nf1, E1, E1b, jtab);
    k_attn<<<NR / BM, 512, 0, stream>>>(adj, ht, nf1, E1, E1b, jtab, out);
}

// Round 4
// 569.152 us; speedup vs baseline: 1.9678x; 1.1518x over previous
//
#include <hip/hip_runtime.h>
#include <hip/hip_bf16.h>
#include <stdint.h>

#define NR 8192
#define FD 512
#define BM 128    // k_attn rows per band
#define BKC 128   // k_attn j per chunk

typedef __attribute__((ext_vector_type(8))) short s8v;   // 8 bf16 (4 VGPRs) - MFMA A/B frag
typedef __attribute__((ext_vector_type(4))) float f32x4; // MFMA C/D frag

static __device__ __forceinline__ short bf16_rtne(float x) {
    union { float f; uint32_t u; } v; v.f = x;
    uint32_t r = (v.u + 0x7FFFu + ((v.u >> 16) & 1u)) >> 16;
    return (short)r;
}
static __device__ __forceinline__ float bf16_to_f32(short s) {
    union { uint32_t u; float f; } v; v.u = ((uint32_t)(uint16_t)s) << 16;
    return v.f;
}
static __device__ __forceinline__ float asfloat_u32(uint32_t u) {
    union { uint32_t u; float f; } v; v.u = u; return v.f;
}

// ---------------- K0: adj -> bitmask (row-major u32 words) ----------------
// thread t: row = t>>8, jw = t&255; reads adj[row][jw*32..+31], writes bm[t].
__global__ void k_prepack(const int* __restrict__ adj, uint32_t* __restrict__ bm) {
    int t = blockIdx.x * 256 + threadIdx.x;          // 2,097,152 threads
    const int4* p = (const int4*)(adj + (size_t)t * 32);
    uint32_t word = 0;
#pragma unroll
    for (int g = 0; g < 8; ++g) {
        int4 v = p[g];
        word |= (uint32_t)(v.x != 0) << (g * 4);
        word |= (uint32_t)(v.y != 0) << (g * 4 + 1);
        word |= (uint32_t)(v.z != 0) << (g * 4 + 2);
        word |= (uint32_t)(v.w != 0) << (g * 4 + 3);
    }
    bm[t] = word;
}

// ---------------- K0a: fp32 -> bf16 convert (inp) ----------------
__global__ void k_convert(const float* __restrict__ in, short* __restrict__ out) {
    int i = blockIdx.x * blockDim.x + threadIdx.x;   // one float4 per thread
    float4 v = ((const float4*)in)[i];
    short4 s;
    s.x = bf16_rtne(v.x); s.y = bf16_rtne(v.y);
    s.z = bf16_rtne(v.z); s.w = bf16_rtne(v.w);
    ((short4*)out)[i] = s;
}

// ---------------- K0b: W1 [k][n] -> W1T bf16 [n][k] ----------------
__global__ void k_w1t(const float* __restrict__ W1, short* __restrict__ W1T) {
    int i = blockIdx.x * 256 + threadIdx.x;  // 512*512
    int k = i & 511, n = i >> 9;
    W1T[(size_t)n * 512 + k] = bf16_rtne(W1[(size_t)k * 512 + n]);
}

// ---------------- K1: h = inp @ W1 + b1 ; writes h AND ht2 ----------------
// block 32r x 128c, 256 thr (4 waves, wave = 32x32). grid (256,4) = 1024 blocks.
// ht2 layout: [jt=row/32][col][row%32] bf16 (tile-contiguous for k_attn B-frags)
__launch_bounds__(256)
__global__ void k_gemm_h(const short* __restrict__ A,   // inp bf16 [8192][512]
                         const short* __restrict__ BT,  // W1T bf16 [512][512]
                         const float* __restrict__ b1,
                         short* __restrict__ H,         // bf16 [8192][512]
                         short* __restrict__ HT2)       // bf16 [256][512][32]
{
    const int lane = threadIdx.x & 63;
    const int wn   = threadIdx.x >> 6;     // 0..3
    const int m    = lane & 15;
    const int q    = lane >> 4;
    const int r0   = blockIdx.x * 32;
    const int c0   = blockIdx.y * 128 + wn * 32;

    f32x4 acc[2][2] = {};
#pragma unroll 1
    for (int k0 = 0; k0 < 512; k0 += 32) {
        s8v a[2], b[2];
#pragma unroll
        for (int rt = 0; rt < 2; ++rt)
            a[rt] = *(const s8v*)(A + (size_t)(r0 + rt * 16 + m) * 512 + k0 + q * 8);
#pragma unroll
        for (int nt = 0; nt < 2; ++nt)
            b[nt] = *(const s8v*)(BT + (size_t)(c0 + nt * 16 + m) * 512 + k0 + q * 8);
#pragma unroll
        for (int rt = 0; rt < 2; ++rt)
#pragma unroll
            for (int nt = 0; nt < 2; ++nt)
                acc[rt][nt] = __builtin_amdgcn_mfma_f32_16x16x32_bf16(a[rt], b[nt], acc[rt][nt], 0, 0, 0);
    }
    float b1v[2];
#pragma unroll
    for (int nt = 0; nt < 2; ++nt) b1v[nt] = b1[c0 + nt * 16 + m];

#pragma unroll
    for (int rt = 0; rt < 2; ++rt)
#pragma unroll
        for (int nt = 0; nt < 2; ++nt) {
            int col = c0 + nt * 16 + m;
            short4 hp;
#pragma unroll
            for (int r = 0; r < 4; ++r) {
                int row = r0 + rt * 16 + q * 4 + r;
                short hv = bf16_rtne(acc[rt][nt][r] + b1v[nt]);
                H[(size_t)row * 512 + col] = hv;
                ((short*)&hp)[r] = hv;
            }
            // rows rt*16+q*4..+3 within 32-tile (jt = blockIdx.x)
            *(short4*)(HT2 + (size_t)blockIdx.x * (512 * 32) + (size_t)col * 32 + rt * 16 + q * 4) = hp;
        }
}

// ---------------- K3: f1/f2 + separable-exp tables ----------------
// w_ij = adj ? (f2s_j >= -f1_i ? E1_i*E2_j : E1b_i*E2b_j) : 0
__global__ void k_f1f2(const short* __restrict__ H, const float* __restrict__ a1,
                       const float* __restrict__ a2, const float* __restrict__ b2,
                       float* __restrict__ nf1, float* __restrict__ E1,
                       float* __restrict__ E1b, uint2* __restrict__ jtab)
{
    const int lane = threadIdx.x & 63;
    const int row  = blockIdx.x * 4 + (threadIdx.x >> 6);
    s8v hv = *(const s8v*)(H + (size_t)row * 512 + lane * 8);
    float4 a1l = ((const float4*)(a1 + lane * 8))[0];
    float4 a1h = ((const float4*)(a1 + lane * 8))[1];
    float4 a2l = ((const float4*)(a2 + lane * 8))[0];
    float4 a2h = ((const float4*)(a2 + lane * 8))[1];
    float hf[8];
#pragma unroll
    for (int i = 0; i < 8; ++i) hf[i] = bf16_to_f32(hv[i]);
    float s1 = hf[0] * a1l.x + hf[1] * a1l.y + hf[2] * a1l.z + hf[3] * a1l.w
             + hf[4] * a1h.x + hf[5] * a1h.y + hf[6] * a1h.z + hf[7] * a1h.w;
    float s2 = hf[0] * a2l.x + hf[1] * a2l.y + hf[2] * a2l.z + hf[3] * a2l.w
             + hf[4] * a2h.x + hf[5] * a2h.y + hf[6] * a2h.z + hf[7] * a2h.w;
#pragma unroll
    for (int o = 32; o > 0; o >>= 1) {
        s1 += __shfl_xor(s1, o);
        s2 += __shfl_xor(s2, o);
    }
    if (lane == 0) {
        float f1v = s1;
        float f2v = s2 + b2[0];
        nf1[row]  = -f1v;
        E1[row]   = __expf(f1v);
        E1b[row]  = __expf(0.2f * f1v);
        uint32_t p = (uint32_t)(uint16_t)bf16_rtne(__expf(f2v))
                   | ((uint32_t)(uint16_t)bf16_rtne(__expf(0.2f * f2v)) << 16);
        union { float f; uint32_t u; } fb; fb.f = f2v;
        jtab[row] = make_uint2(p, fb.u);
    }
}

// ---------------- K4: fused masked-softmax attention @ h (partials) --------
// grid 512 = 64 bands x 4 col-blocks x 2 j-splits; 2 blocks/CU resident.
// 512 thr / 8 waves: wm in {0,1} (64 rows), wn in {0..3} (32 cols).
// Per 128-j chunk: phase1 builds 128x128 bf16 weight tile (XOR-swizzled LDS,
// each thread: 4 rows x 8 j from bitmask+jtab), one barrier, phase2 = 4
// barrier-free k-steps (4 ds_read A + 2 contiguous-1KB global B + 8 MFMA).
__launch_bounds__(512, 4)
__global__ void k_attn(const uint32_t* __restrict__ bm,  // [8192][256]
                       const short* __restrict__ HT2,    // [256][512][32]
                       const float* __restrict__ nf1,
                       const float* __restrict__ E1,
                       const float* __restrict__ E1b,
                       const uint2* __restrict__ jtab,
                       float* __restrict__ nump,         // [2][8192][512]
                       float* __restrict__ denomp)       // [2][8192]
{
    __shared__ __align__(16) short wt[2][BM * BKC];      // 64 KB

    const int t    = threadIdx.x;
    const int lane = t & 63;
    const int w    = t >> 6;
    const int wm   = w & 1;
    const int wn   = w >> 1;
    const int m    = lane & 15;
    const int q    = lane >> 4;

    const int band = blockIdx.x >> 3;
    const int cb   = (blockIdx.x >> 1) & 3;
    const int js   = blockIdx.x & 1;
    const int r0   = band * BM;
    const int jsb  = js * 4096;

    // producer coords: 4 rows x 8 j per thread
    const int rowq = t >> 4;           // 0..31 -> rows rowq*4..+3
    const int jg   = t & 15;           // 8-j group within chunk
    const int byteoff = (jg & 3) * 8;

    float nf1v[4], e1v[4], e1bv[4];
#pragma unroll
    for (int r = 0; r < 4; ++r) {
        int rr = r0 + rowq * 4 + r;
        nf1v[r] = nf1[rr]; e1v[r] = E1[rr]; e1bv[r] = E1b[rr];
    }
    const uint32_t* bmp = bm + (size_t)(r0 + rowq * 4) * 256 + (jsb >> 5) + (jg >> 2);
    const uint4*   tabp = (const uint4*)jtab + ((jsb + jg * 8) >> 1);

    const int colbase = cb * 128 + wn * 32;
    const short* htp = HT2 + (size_t)(jsb >> 5) * 16384 + q * 8;

    f32x4 acc[4][2] = {};
    float dsum[4] = {0.f, 0.f, 0.f, 0.f};

#pragma unroll 1
    for (int ch = 0; ch < 4096 / BKC; ++ch) {
        const int p = ch & 1;
        // ---- phase 1
        uint32_t bw[4];
#pragma unroll
        for (int r = 0; r < 4; ++r) bw[r] = bmp[(size_t)r * 256 + ch * 4];
        uint4 tb[4];
#pragma unroll
        for (int i = 0; i < 4; ++i) tb[i] = tabp[ch * 64 + i];
        const uint32_t* tw = (const uint32_t*)tb;

#pragma unroll
        for (int r = 0; r < 4; ++r) {
            uint32_t byte = (bw[r] >> byteoff) & 0xFFu;
            s8v wv;
            float ds = 0.f;
#pragma unroll
            for (int jj = 0; jj < 8; ++jj) {
                uint32_t pk  = tw[jj * 2];
                float e2  = asfloat_u32(pk << 16);
                float e2b = asfloat_u32(pk & 0xFFFF0000u);
                float f2  = asfloat_u32(tw[jj * 2 + 1]);
                bool  c   = (f2 >= nf1v[r]);
                float wgt = c ? (e1v[r] * e2) : (e1bv[r] * e2b);
                wgt = ((byte >> jj) & 1u) ? wgt : 0.f;
                ds += wgt;
                wv[jj] = bf16_rtne(wgt);
            }
            dsum[r] += ds;
            int row  = rowq * 4 + r;
            int slot = jg ^ (row & 15);
            *(s8v*)&wt[p][row * BKC + slot * 8] = wv;
        }

        __syncthreads();

        // ---- phase 2: 4 barrier-free k-steps
#pragma unroll
        for (int kk = 0; kk < 4; ++kk) {
            s8v b[2];
#pragma unroll
            for (int nt = 0; nt < 2; ++nt)
                b[nt] = *(const s8v*)(htp + (size_t)(ch * 4 + kk) * 16384 + (colbase + nt * 16 + m) * 32);
            const int sb = kk * 4 + q;
            s8v af[4];
#pragma unroll
            for (int i = 0; i < 4; ++i) {
                int row = wm * 64 + i * 16 + m;
                af[i] = *(const s8v*)&wt[p][row * BKC + ((sb ^ m) << 3)];
            }
#pragma unroll
            for (int i = 0; i < 4; ++i)
#pragma unroll
                for (int nt = 0; nt < 2; ++nt)
                    acc[i][nt] = __builtin_amdgcn_mfma_f32_16x16x32_bf16(af[i], b[nt], acc[i][nt], 0, 0, 0);
        }
    }

    // ---- partial denominators (per j-split); only cb==0 writes
#pragma unroll
    for (int r = 0; r < 4; ++r) {
#pragma unroll
        for (int o = 1; o < 16; o <<= 1) dsum[r] += __shfl_xor(dsum[r], o);
    }
    if (cb == 0 && jg == 0) {
#pragma unroll
        for (int r = 0; r < 4; ++r)
            denomp[(size_t)js * NR + r0 + rowq * 4 + r] = dsum[r];
    }

    // ---- partial numerators
    float* np = nump + (size_t)js * NR * FD;
#pragma unroll
    for (int i = 0; i < 4; ++i)
#pragma unroll
        for (int nt = 0; nt < 2; ++nt)
#pragma unroll
            for (int r = 0; r < 4; ++r) {
                int row = r0 + wm * 64 + i * 16 + q * 4 + r;
                int col = colbase + nt * 16 + m;
                np[(size_t)row * FD + col] = acc[i][nt][r];
            }
}

// ---------------- K5: combine j-split partials, softmax divide, ELU --------
__global__ void k_combine(const float* __restrict__ nump,
                          const float* __restrict__ denomp,
                          float* __restrict__ out)
{
    size_t e = ((size_t)blockIdx.x * 256 + threadIdx.x) * 4;
    int row = (int)(e >> 9);
    float4 n0 = *(const float4*)(nump + e);
    float4 n1 = *(const float4*)(nump + (size_t)NR * FD + e);
    float d = denomp[row] + denomp[NR + row];
    float inv = 1.0f / d;
    float4 o;
    o.x = (n0.x + n1.x) * inv; o.y = (n0.y + n1.y) * inv;
    o.z = (n0.z + n1.z) * inv; o.w = (n0.w + n1.w) * inv;
    o.x = (o.x > 0.f) ? o.x : (__expf(o.x) - 1.f);
    o.y = (o.y > 0.f) ? o.y : (__expf(o.y) - 1.f);
    o.z = (o.z > 0.f) ? o.z : (__expf(o.z) - 1.f);
    o.w = (o.w > 0.f) ? o.w : (__expf(o.w) - 1.f);
    *(float4*)(out + e) = o;
}

extern "C" void kernel_launch(void* const* d_in, const int* in_sizes, int n_in,
                              void* d_out, int out_size, void* d_ws, size_t ws_size,
                              hipStream_t stream) {
    const float* inp = (const float*)d_in[0];
    const int*   adj = (const int*)d_in[1];
    const float* W1  = (const float*)d_in[2];
    const float* b1  = (const float*)d_in[3];
    const float* a1  = (const float*)d_in[4];
    const float* a2  = (const float*)d_in[5];
    const float* b2  = (const float*)d_in[6];
    float* out = (float*)d_out;

    // workspace layout
    short*    inp_bf = (short*)d_ws;                        // 8 MB
    short*    w1t    = inp_bf + (size_t)NR * FD;            // 0.5 MB
    short*    h      = w1t + (size_t)FD * FD;               // 8 MB
    short*    ht2    = h + (size_t)NR * FD;                 // 8 MB
    uint32_t* bmw    = (uint32_t*)(ht2 + (size_t)FD * NR);  // 8 MB
    float*    nf1    = (float*)(bmw + (size_t)NR * 256);
    float*    E1     = nf1 + NR;
    float*    E1b    = E1 + NR;
    uint2*    jtab   = (uint2*)(E1b + NR);                  // 64 KB
    float*    nump   = (float*)(jtab + NR);                 // 32 MB
    float*    denomp = nump + (size_t)2 * NR * FD;          // 64 KB

    k_prepack<<<NR * 256 / 256, 256, 0, stream>>>(adj, bmw);
    k_convert<<<(NR * FD / 4) / 256, 256, 0, stream>>>(inp, inp_bf);
    k_w1t<<<(FD * FD) / 256, 256, 0, stream>>>(W1, w1t);
    dim3 g1(NR / 32, FD / 128);
    k_gemm_h<<<g1, 256, 0, stream>>>(inp_bf, w1t, b1, h, ht2);
    k_f1f2<<<NR / 4, 256, 0, stream>>>(h, a1, a2, b2, nf1, E1, E1b, jtab);
    k_attn<<<(NR / BM) * 4 * 2, 512, 0, stream>>>(bmw, ht2, nf1, E1, E1b, jtab, nump, denomp);
    k_combine<<<(NR * FD / 4) / 256, 256, 0, stream>>>(nump, denomp, out);
}

// Round 5
// 523.840 us; speedup vs baseline: 2.1380x; 1.0865x over previous
//
#include <hip/hip_runtime.h>
#include <hip/hip_bf16.h>
#include <stdint.h>

#define NR 8192
#define FD 512
#define BM 128    // k_attn rows per band
#define BKC 128   // k_attn j per chunk

typedef __attribute__((ext_vector_type(8))) short s8v;   // 8 bf16 (4 VGPRs) - MFMA A/B frag
typedef __attribute__((ext_vector_type(4))) float f32x4; // MFMA C/D frag

static __device__ __forceinline__ short bf16_rtne(float x) {
    union { float f; uint32_t u; } v; v.f = x;
    uint32_t r = (v.u + 0x7FFFu + ((v.u >> 16) & 1u)) >> 16;
    return (short)r;
}
static __device__ __forceinline__ float bf16_to_f32(short s) {
    union { uint32_t u; float f; } v; v.u = ((uint32_t)(uint16_t)s) << 16;
    return v.f;
}

// ---------------- K0a: fp32 -> bf16 convert (inp) ----------------
__global__ void k_convert(const float* __restrict__ in, short* __restrict__ out) {
    int i = blockIdx.x * blockDim.x + threadIdx.x;   // one float4 per thread
    float4 v = ((const float4*)in)[i];
    short4 s;
    s.x = bf16_rtne(v.x); s.y = bf16_rtne(v.y);
    s.z = bf16_rtne(v.z); s.w = bf16_rtne(v.w);
    ((short4*)out)[i] = s;
}

// ---------------- K0b: W1 [k][n] -> W1T bf16 [n][k] ----------------
__global__ void k_w1t(const float* __restrict__ W1, short* __restrict__ W1T) {
    int i = blockIdx.x * 256 + threadIdx.x;  // 512*512
    int k = i & 511, n = i >> 9;
    W1T[(size_t)n * 512 + k] = bf16_rtne(W1[(size_t)k * 512 + n]);
}

// ---------------- K1: h = inp @ W1 + b1 ; writes h AND ht2 ----------------
// block 32r x 128c, 256 thr (4 waves, wave = 32x32). grid (256,4) = 1024 blocks.
// ht2 layout: [jt=row/32][col][row%32] bf16 (tile-contiguous for k_attn B-frags)
__launch_bounds__(256)
__global__ void k_gemm_h(const short* __restrict__ A,   // inp bf16 [8192][512]
                         const short* __restrict__ BT,  // W1T bf16 [512][512]
                         const float* __restrict__ b1,
                         short* __restrict__ H,         // bf16 [8192][512]
                         short* __restrict__ HT2)       // bf16 [256][512][32]
{
    const int lane = threadIdx.x & 63;
    const int wn   = threadIdx.x >> 6;     // 0..3
    const int m    = lane & 15;
    const int q    = lane >> 4;
    const int r0   = blockIdx.x * 32;
    const int c0   = blockIdx.y * 128 + wn * 32;

    f32x4 acc[2][2] = {};
#pragma unroll 1
    for (int k0 = 0; k0 < 512; k0 += 32) {
        s8v a[2], b[2];
#pragma unroll
        for (int rt = 0; rt < 2; ++rt)
            a[rt] = *(const s8v*)(A + (size_t)(r0 + rt * 16 + m) * 512 + k0 + q * 8);
#pragma unroll
        for (int nt = 0; nt < 2; ++nt)
            b[nt] = *(const s8v*)(BT + (size_t)(c0 + nt * 16 + m) * 512 + k0 + q * 8);
#pragma unroll
        for (int rt = 0; rt < 2; ++rt)
#pragma unroll
            for (int nt = 0; nt < 2; ++nt)
                acc[rt][nt] = __builtin_amdgcn_mfma_f32_16x16x32_bf16(a[rt], b[nt], acc[rt][nt], 0, 0, 0);
    }
    float b1v[2];
#pragma unroll
    for (int nt = 0; nt < 2; ++nt) b1v[nt] = b1[c0 + nt * 16 + m];

#pragma unroll
    for (int rt = 0; rt < 2; ++rt)
#pragma unroll
        for (int nt = 0; nt < 2; ++nt) {
            int col = c0 + nt * 16 + m;
            short4 hp;
#pragma unroll
            for (int r = 0; r < 4; ++r) {
                int row = r0 + rt * 16 + q * 4 + r;
                short hv = bf16_rtne(acc[rt][nt][r] + b1v[nt]);
                H[(size_t)row * 512 + col] = hv;
                ((short*)&hp)[r] = hv;
            }
            *(short4*)(HT2 + (size_t)blockIdx.x * (512 * 32) + (size_t)col * 32 + rt * 16 + q * 4) = hp;
        }
}

// ---------------- K3: f1 = h@a1, f2s = h@a2 + b2 ----------------
__global__ void k_f1f2(const short* __restrict__ H, const float* __restrict__ a1,
                       const float* __restrict__ a2, const float* __restrict__ b2,
                       float* __restrict__ f1, float* __restrict__ f2s)
{
    const int lane = threadIdx.x & 63;
    const int row  = blockIdx.x * 4 + (threadIdx.x >> 6);
    s8v hv = *(const s8v*)(H + (size_t)row * 512 + lane * 8);
    float4 a1l = ((const float4*)(a1 + lane * 8))[0];
    float4 a1h = ((const float4*)(a1 + lane * 8))[1];
    float4 a2l = ((const float4*)(a2 + lane * 8))[0];
    float4 a2h = ((const float4*)(a2 + lane * 8))[1];
    float hf[8];
#pragma unroll
    for (int i = 0; i < 8; ++i) hf[i] = bf16_to_f32(hv[i]);
    float s1 = hf[0] * a1l.x + hf[1] * a1l.y + hf[2] * a1l.z + hf[3] * a1l.w
             + hf[4] * a1h.x + hf[5] * a1h.y + hf[6] * a1h.z + hf[7] * a1h.w;
    float s2 = hf[0] * a2l.x + hf[1] * a2l.y + hf[2] * a2l.z + hf[3] * a2l.w
             + hf[4] * a2h.x + hf[5] * a2h.y + hf[6] * a2h.z + hf[7] * a2h.w;
#pragma unroll
    for (int o = 32; o > 0; o >>= 1) {
        s1 += __shfl_xor(s1, o);
        s2 += __shfl_xor(s2, o);
    }
    if (lane == 0) {
        f1[row]  = s1;
        f2s[row] = s2 + b2[0];
    }
}

// ---------------- K4: fused masked-softmax attention @ h (partials) --------
// grid 256 = 64 bands x 4 j-splits; 1 block/CU, 1024 thr = 16 waves.
// Block covers ALL 512 cols -> every weight computed exactly once; adj
// streamed raw (each element read once, coalesced). Wave tile 64r x 64c.
// Per 128-j chunk: phase1: each thread computes 16 weights (1 row x 16 j)
// = exp(leaky(f1_i+f2_j)) masked, into XOR-swizzled LDS; one barrier;
// phase2: 4 barrier-free k-steps (ds_read A-frags, contiguous HT2 B-frags).
__launch_bounds__(1024)
__global__ void k_attn(const int* __restrict__ adj,    // [8192][8192]
                       const short* __restrict__ HT2,  // [256][512][32]
                       const float* __restrict__ f1,
                       const float* __restrict__ f2s,
                       float* __restrict__ nump,       // [4][8192][512]
                       float* __restrict__ denomp)     // [4][8192]
{
    __shared__ __align__(16) short wt[2][BM * BKC];    // 64 KB

    const int t    = threadIdx.x;
    const int lane = t & 63;
    const int w    = t >> 6;          // 0..15
    const int wr   = w & 1;           // row half (64 rows)
    const int wc   = w >> 1;          // 0..7  col group (64 cols)
    const int m    = lane & 15;
    const int q    = lane >> 4;

    const int band = blockIdx.x & 63;
    const int js   = blockIdx.x >> 6; // 0..3
    const int r0   = band * BM;
    const int jb0  = js * 2048;

    // producer: 1 row x 16 j per thread
    const int prow = t >> 3;          // 0..127
    const int jg   = t & 7;           // 16-j group within 128-chunk

    const float f1v = f1[r0 + prow];
    const int*   adjp = adj + (size_t)(r0 + prow) * NR + jb0 + jg * 16;
    const float* f2p  = f2s + jb0 + jg * 16;

    f32x4 acc[4][4] = {};
    float dsum = 0.f;

#pragma unroll 1
    for (int ch = 0; ch < 2048 / BKC; ++ch) {
        const int p = ch & 1;
        // ---- phase 1: 16 weights ----
        int4   aj[4];
        float4 fv[4];
#pragma unroll
        for (int g = 0; g < 4; ++g) {
            aj[g] = ((const int4*)(adjp + ch * BKC))[g];
            fv[g] = ((const float4*)(f2p + ch * BKC))[g];
        }
        float wgt[16];
#pragma unroll
        for (int jj = 0; jj < 16; ++jj) {
            int   a  = ((const int*)aj)[jj];
            float s  = f1v + ((const float*)fv)[jj];
            float l  = fmaxf(s, 0.2f * s);
            float e  = __expf(l);
            float wv = (a != 0) ? e : 0.f;
            dsum += wv;
            wgt[jj] = wv;
        }
        s8v wv0, wv1;
#pragma unroll
        for (int jj = 0; jj < 8; ++jj) {
            wv0[jj] = bf16_rtne(wgt[jj]);
            wv1[jj] = bf16_rtne(wgt[8 + jj]);
        }
        const int sw = prow & 15;
        *(s8v*)&wt[p][prow * BKC + (((2 * jg) ^ sw) << 3)]     = wv0;
        *(s8v*)&wt[p][prow * BKC + (((2 * jg + 1) ^ sw) << 3)] = wv1;

        __syncthreads();

        // ---- phase 2: 4 barrier-free k-steps ----
#pragma unroll
        for (int kk = 0; kk < 4; ++kk) {
            const int jt = (jb0 + ch * BKC + kk * 32) >> 5;
            const short* hb = HT2 + (size_t)jt * 16384 + q * 8;
            s8v af[4];
#pragma unroll
            for (int i = 0; i < 4; ++i) {
                int row = wr * 64 + i * 16 + m;
                af[i] = *(const s8v*)&wt[p][row * BKC + (((kk * 4 + q) ^ m) << 3)];
            }
#pragma unroll
            for (int nt = 0; nt < 4; ++nt) {
                s8v b = *(const s8v*)(hb + (size_t)(wc * 64 + nt * 16 + m) * 32);
#pragma unroll
                for (int i = 0; i < 4; ++i)
                    acc[i][nt] = __builtin_amdgcn_mfma_f32_16x16x32_bf16(af[i], b, acc[i][nt], 0, 0, 0);
            }
        }
    }

    // ---- partial denominators: reduce over the 8 producer threads per row
    dsum += __shfl_xor(dsum, 1);
    dsum += __shfl_xor(dsum, 2);
    dsum += __shfl_xor(dsum, 4);
    if (jg == 0) denomp[(size_t)js * NR + r0 + prow] = dsum;

    // ---- partial numerators
    float* np = nump + (size_t)js * NR * FD;
#pragma unroll
    for (int i = 0; i < 4; ++i)
#pragma unroll
        for (int nt = 0; nt < 4; ++nt)
#pragma unroll
            for (int r = 0; r < 4; ++r) {
                int row = r0 + wr * 64 + i * 16 + q * 4 + r;
                int col = wc * 64 + nt * 16 + m;
                np[(size_t)row * FD + col] = acc[i][nt][r];
            }
}

// ---------------- K5: combine j-split partials, softmax divide, ELU --------
__global__ void k_combine(const float* __restrict__ nump,
                          const float* __restrict__ denomp,
                          float* __restrict__ out)
{
    size_t e = ((size_t)blockIdx.x * 256 + threadIdx.x) * 4;
    int row = (int)(e >> 9);
    float4 n0 = *(const float4*)(nump + e);
    float4 n1 = *(const float4*)(nump + (size_t)NR * FD + e);
    float4 n2 = *(const float4*)(nump + (size_t)2 * NR * FD + e);
    float4 n3 = *(const float4*)(nump + (size_t)3 * NR * FD + e);
    float d = denomp[row] + denomp[NR + row] + denomp[2 * NR + row] + denomp[3 * NR + row];
    float inv = 1.0f / d;
    float4 o;
    o.x = (n0.x + n1.x + n2.x + n3.x) * inv;
    o.y = (n0.y + n1.y + n2.y + n3.y) * inv;
    o.z = (n0.z + n1.z + n2.z + n3.z) * inv;
    o.w = (n0.w + n1.w + n2.w + n3.w) * inv;
    o.x = (o.x > 0.f) ? o.x : (__expf(o.x) - 1.f);
    o.y = (o.y > 0.f) ? o.y : (__expf(o.y) - 1.f);
    o.z = (o.z > 0.f) ? o.z : (__expf(o.z) - 1.f);
    o.w = (o.w > 0.f) ? o.w : (__expf(o.w) - 1.f);
    *(float4*)(out + e) = o;
}

extern "C" void kernel_launch(void* const* d_in, const int* in_sizes, int n_in,
                              void* d_out, int out_size, void* d_ws, size_t ws_size,
                              hipStream_t stream) {
    const float* inp = (const float*)d_in[0];
    const int*   adj = (const int*)d_in[1];
    const float* W1  = (const float*)d_in[2];
    const float* b1  = (const float*)d_in[3];
    const float* a1  = (const float*)d_in[4];
    const float* a2  = (const float*)d_in[5];
    const float* b2  = (const float*)d_in[6];
    float* out = (float*)d_out;

    // workspace layout
    short* inp_bf = (short*)d_ws;                        // 8 MB
    short* w1t    = inp_bf + (size_t)NR * FD;            // 0.5 MB
    short* h      = w1t + (size_t)FD * FD;               // 8 MB
    short* ht2    = h + (size_t)NR * FD;                 // 8 MB
    float* f1     = (float*)(ht2 + (size_t)FD * NR);     // 32 KB
    float* f2s    = f1 + NR;                             // 32 KB
    float* nump   = f2s + NR;                            // 64 MB
    float* denomp = nump + (size_t)4 * NR * FD;          // 128 KB

    k_convert<<<(NR * FD / 4) / 256, 256, 0, stream>>>(inp, inp_bf);
    k_w1t<<<(FD * FD) / 256, 256, 0, stream>>>(W1, w1t);
    dim3 g1(NR / 32, FD / 128);
    k_gemm_h<<<g1, 256, 0, stream>>>(inp_bf, w1t, b1, h, ht2);
    k_f1f2<<<NR / 4, 256, 0, stream>>>(h, a1, a2, b2, f1, f2s);
    k_attn<<<64 * 4, 1024, 0, stream>>>(adj, ht2, f1, f2s, nump, denomp);
    k_combine<<<(NR * FD / 4) / 256, 256, 0, stream>>>(nump, denomp, out);
}